// Round 5
// baseline (128.838 us; speedup 1.0000x reference)
//
#include <hip/hip_runtime.h>
#include <hip/hip_cooperative_groups.h>

namespace cg = cooperative_groups;

#define BN 512
#define DIM 128
#define TMARGIN 0.3f
#define NT 256
#define NW 4   // waves per block

#define FMA4(ACC, U, V)                                                \
    ACC.x += U.x * V.x; ACC.y += U.y * V.y;                            \
    ACC.z += U.z * V.z; ACC.w += U.w * V.w;

__device__ __forceinline__ float hsum4(float4 v) {
    return (v.x + v.y) + (v.z + v.w);
}

// ---------------------------------------------------------------------------
// Single cooperative kernel, 512 blocks x 256 threads (2 blocks/CU).
// Phase A: block b computes a K-half (b&1) of a 32x32 d^2 tile (b>>1),
//          writing d2part[h][i][j] = sq_h(i)+sq_h(j)-2*dot_h(i,j).
// grid.sync()
// Phase B: block i scans dist row i (sqrt of the two halves' sum) for
//          semi-hard triplets; ticketed finalize writes the scalar loss.
// ---------------------------------------------------------------------------
__global__ __launch_bounds__(NT, 2) void fused_coop_kernel(
        const float* __restrict__ emb,
        const int* __restrict__ labels,
        float* __restrict__ d2part,     // 2 * BN * BN floats
        float* __restrict__ accum,      // [0]=sum, [1]=cnt, [2]=ticket(int)
        float* __restrict__ out) {
    const int b   = blockIdx.x;
    const int tid = threadIdx.x;

    // ---------------- Phase A: partial d^2 GEMM ----------------
    {
        const int tile = b >> 1;
        const int h    = b & 1;
        const int tr0  = (tile >> 4) * 32;
        const int tc0  = (tile & 15) * 32;

        __shared__ float4 Af[16][33];
        __shared__ float4 Bf[16][33];

        if (b == 0 && tid == 0) {
            accum[0] = 0.f; accum[1] = 0.f; ((int*)accum)[2] = 0;
        }

        const float4* emb4 = (const float4*)emb;
        const int h16 = h * 16;
#pragma unroll
        for (int s = 0; s < 2; ++s) {
            const int idx = s * NT + tid;   // 0..511
            const int r   = idx >> 4;       // 0..31
            const int c4  = idx & 15;       // 0..15
            Af[c4][r] = emb4[(size_t)(tr0 + r) * 32 + h16 + c4];
            Bf[c4][r] = emb4[(size_t)(tc0 + r) * 32 + h16 + c4];
        }
        __syncthreads();

        const int tr = (tid >> 4) << 1;  // 0,2,...,30
        const int tc = tid & 15;         // cols tc, tc+16

        float4 acc00 = {0,0,0,0}, acc01 = {0,0,0,0};
        float4 acc10 = {0,0,0,0}, acc11 = {0,0,0,0};
        float4 sa0   = {0,0,0,0}, sa1   = {0,0,0,0};
        float4 sb0   = {0,0,0,0}, sb1   = {0,0,0,0};
#pragma unroll
        for (int k4 = 0; k4 < 16; ++k4) {
            const float4 a0 = Af[k4][tr];
            const float4 a1 = Af[k4][tr + 1];
            const float4 b0 = Bf[k4][tc];
            const float4 b1 = Bf[k4][tc + 16];
            FMA4(acc00, a0, b0); FMA4(acc01, a0, b1);
            FMA4(acc10, a1, b0); FMA4(acc11, a1, b1);
            FMA4(sa0, a0, a0);   FMA4(sa1, a1, a1);
            FMA4(sb0, b0, b0);   FMA4(sb1, b1, b1);
        }

        const float qa0 = hsum4(sa0), qa1 = hsum4(sa1);
        const float qb0 = hsum4(sb0), qb1 = hsum4(sb1);
        float* outp = d2part + (size_t)h * BN * BN;
        const int r0 = tr0 + tr, c0 = tc0 + tc;
        outp[(size_t)r0 * BN + c0]            = qa0 + qb0 - 2.f * hsum4(acc00);
        outp[(size_t)r0 * BN + c0 + 16]       = qa0 + qb1 - 2.f * hsum4(acc01);
        outp[(size_t)(r0 + 1) * BN + c0]      = qa1 + qb0 - 2.f * hsum4(acc10);
        outp[(size_t)(r0 + 1) * BN + c0 + 16] = qa1 + qb1 - 2.f * hsum4(acc11);
    }

    cg::this_grid().sync();

    // ---------------- Phase B: semi-hard triplet scan ----------------
    {
        const int i    = b;
        const int lane = tid & 63;
        const int wave = tid >> 6;

        __shared__ float drow[BN];
        __shared__ int   lab[BN];
        __shared__ int   pos_idx[BN];
        __shared__ int   npos_s;
        __shared__ float wsum[NW];
        __shared__ int   wcnt[NW];

        {
            const float2 va = *(const float2*)&d2part[(size_t)i * BN + 2 * tid];
            const float2 vb = *(const float2*)&d2part[(size_t)BN * BN +
                                                      (size_t)i * BN + 2 * tid];
            drow[2 * tid]     = sqrtf(fmaxf(va.x + vb.x, 1e-12f));
            drow[2 * tid + 1] = sqrtf(fmaxf(va.y + vb.y, 1e-12f));
        }
        lab[tid]       = labels[tid];
        lab[tid + 256] = labels[tid + 256];
        if (tid == 0) npos_s = 0;
        __syncthreads();

        const int li = lab[i];

        for (int j = tid; j < BN; j += NT) {
            if (lab[j] == li && j != i) {
                int p = atomicAdd(&npos_s, 1);
                pos_idx[p] = j;
            }
        }

        // Per-wave min over negatives + has_neg (barrier-free).
        float mn = 1e30f;
        int   hn = 0;
        for (int k = lane; k < BN; k += 64) {
            if (lab[k] != li) { hn = 1; mn = fminf(mn, drow[k]); }
        }
#pragma unroll
        for (int off = 32; off > 0; off >>= 1) {
            mn = fminf(mn, __shfl_down(mn, off));
            hn |= __shfl_down(hn, off);
        }
        mn = __shfl(mn, 0);
        hn = __shfl(hn, 0);
        __syncthreads();  // npos_s / pos_idx ready

        float lsum = 0.f;
        int   lcnt = 0;
        const int npos = npos_s;
        if (hn) {
            for (int p = wave; p < npos; p += NW) {
                const float dap = drow[pos_idx[p]];
                const float hi  = dap + TMARGIN;
                float smax = -1e30f;
                for (int k = lane; k < BN; k += 64) {
                    const float dan = drow[k];
                    if (lab[k] != li && dan > dap && dan < hi)
                        smax = fmaxf(smax, dan);
                }
#pragma unroll
                for (int off = 32; off > 0; off >>= 1)
                    smax = fmaxf(smax, __shfl_down(smax, off));
                if (lane == 0) {
                    const float dneg = (smax > -1e29f) ? smax : mn;
                    lsum += fmaxf(dap - dneg + TMARGIN, 0.f);
                    lcnt += 1;
                }
            }
        }
        if (lane == 0) { wsum[wave] = lsum; wcnt[wave] = lcnt; }
        __syncthreads();

        if (tid == 0) {
            float s = 0.f;
            int   c = 0;
#pragma unroll
            for (int w = 0; w < NW; ++w) { s += wsum[w]; c += wcnt[w]; }
            atomicAdd(&accum[0], s);
            atomicAdd(&accum[1], (float)c);
            __threadfence();
            int t = atomicAdd((int*)(accum + 2), 1);
            if (t == BN - 1) {
                const float total = atomicAdd(&accum[0], 0.f);
                const float cnt   = atomicAdd(&accum[1], 0.f);
                out[0] = (cnt > 0.f) ? (total / fmaxf(cnt, 1.f)) : 0.f;
            }
        }
    }
}

extern "C" void kernel_launch(void* const* d_in, const int* in_sizes, int n_in,
                              void* d_out, int out_size, void* d_ws, size_t ws_size,
                              hipStream_t stream) {
    const float* emb    = (const float*)d_in[0];
    const int*   labels = (const int*)d_in[1];
    float*       out    = (float*)d_out;

    float* d2part = (float*)d_ws;                  // 2 * 512*512 floats = 2 MB
    float* accum  = d2part + 2 * (size_t)BN * BN;  // 3 words

    void* args[] = {(void*)&emb, (void*)&labels, (void*)&d2part,
                    (void*)&accum, (void*)&out};
    hipLaunchCooperativeKernel((const void*)fused_coop_kernel,
                               dim3(BN), dim3(NT), args, 0, stream);
}

// Round 6
// 85.314 us; speedup vs baseline: 1.5102x; 1.5102x over previous
//
#include <hip/hip_runtime.h>

#define BN 512
#define DIM 128
#define TMARGIN 0.3f
#define NT 256
#define NW 4   // waves per block

#define FMA4(ACC, U, V)                                                \
    ACC.x += U.x * V.x; ACC.y += U.y * V.y;                            \
    ACC.z += U.z * V.z; ACC.w += U.w * V.w;

__device__ __forceinline__ float hsum4(float4 v) {
    return (v.x + v.y) + (v.z + v.w);
}

// ---------------------------------------------------------------------------
// One block per anchor i (512 blocks, 2/CU). Phase A computes dist row i with
// wave-cooperative coalesced loads (4 lanes per row, 16 rows per wave-iter);
// Phase B is the proven semi-hard scan. accum zeroed by a prior memset node.
// ---------------------------------------------------------------------------
__global__ __launch_bounds__(NT, 2) void triplet_fused_kernel(
        const float* __restrict__ emb,
        const int* __restrict__ labels,
        float* __restrict__ accum,   // [0]=sum, [1]=cnt, [2]=ticket(int)
        float* __restrict__ out) {
    const int i    = blockIdx.x;
    const int tid  = threadIdx.x;
    const int lane = tid & 63;
    const int wave = tid >> 6;

    __shared__ float4 ei4[DIM / 4];   // anchor row (512 B)
    __shared__ float  drow[BN];
    __shared__ int    lab[BN];
    __shared__ int    pos_idx[BN];
    __shared__ int    npos_s;
    __shared__ float  wsum[NW];
    __shared__ int    wcnt[NW];

    const float4* emb4 = (const float4*)emb;

    if (tid < DIM / 4) ei4[tid] = emb4[(size_t)i * 32 + tid];
    lab[tid]       = labels[tid];
    lab[tid + 256] = labels[tid + 256];
    if (tid == 0) npos_s = 0;
    __syncthreads();

    // sq_i (per-thread from LDS broadcasts — cheap, no extra barrier)
    float4 sqv = {0, 0, 0, 0};
#pragma unroll
    for (int q = 0; q < DIM / 4; ++q) { float4 u = ei4[q]; FMA4(sqv, u, u); }
    const float sq_i = hsum4(sqv);

    // ---------------- Phase A: dist row, coalesced ----------------
    // Each wave: 16 rows per iter, 4 lanes per row (lane kl reads float4s
    // k4 = kl + 4q -> 4 consecutive float4 = 64 B contiguous per row group).
    const int rl = lane >> 2;   // row-in-group 0..15
    const int kl = lane & 3;    // k-lane 0..3
#pragma unroll
    for (int c = 0; c < 8; ++c) {
        const int r = c * 64 + wave * 16 + rl;
        float4 accd = {0, 0, 0, 0}, accq = {0, 0, 0, 0};
#pragma unroll
        for (int q = 0; q < 8; ++q) {
            const int k4 = kl + 4 * q;
            const float4 v = emb4[(size_t)r * 32 + k4];
            const float4 u = ei4[k4];
            FMA4(accd, u, v);
            FMA4(accq, v, v);
        }
        float dot = hsum4(accd);
        float sqj = hsum4(accq);
        dot += __shfl_down(dot, 1); dot += __shfl_down(dot, 2);
        sqj += __shfl_down(sqj, 1); sqj += __shfl_down(sqj, 2);
        if (kl == 0) {
            const float d2 = sq_i + sqj - 2.f * dot;
            drow[r] = sqrtf(fmaxf(d2, 1e-12f));
        }
    }
    __syncthreads();

    // ---------------- Phase B: semi-hard scan ----------------
    const int li = lab[i];

    for (int j = tid; j < BN; j += NT) {
        if (lab[j] == li && j != i) {
            int p = atomicAdd(&npos_s, 1);
            pos_idx[p] = j;
        }
    }

    // Per-wave min over negatives + has_neg (barrier-free, redundant per wave).
    float mn = 1e30f;
    int   hn = 0;
    for (int k = lane; k < BN; k += 64) {
        if (lab[k] != li) { hn = 1; mn = fminf(mn, drow[k]); }
    }
#pragma unroll
    for (int off = 32; off > 0; off >>= 1) {
        mn = fminf(mn, __shfl_down(mn, off));
        hn |= __shfl_down(hn, off);
    }
    mn = __shfl(mn, 0);
    hn = __shfl(hn, 0);
    __syncthreads();  // npos_s / pos_idx ready

    float lsum = 0.f;
    int   lcnt = 0;
    const int npos = npos_s;
    if (hn) {
        for (int p = wave; p < npos; p += NW) {
            const float dap = drow[pos_idx[p]];
            const float hi  = dap + TMARGIN;
            float smax = -1e30f;
            for (int k = lane; k < BN; k += 64) {
                const float dan = drow[k];
                if (lab[k] != li && dan > dap && dan < hi)
                    smax = fmaxf(smax, dan);
            }
#pragma unroll
            for (int off = 32; off > 0; off >>= 1)
                smax = fmaxf(smax, __shfl_down(smax, off));
            if (lane == 0) {
                const float dneg = (smax > -1e29f) ? smax : mn;
                lsum += fmaxf(dap - dneg + TMARGIN, 0.f);
                lcnt += 1;
            }
        }
    }
    if (lane == 0) { wsum[wave] = lsum; wcnt[wave] = lcnt; }
    __syncthreads();

    if (tid == 0) {
        float s = 0.f;
        int   c = 0;
#pragma unroll
        for (int w = 0; w < NW; ++w) { s += wsum[w]; c += wcnt[w]; }
        atomicAdd(&accum[0], s);
        atomicAdd(&accum[1], (float)c);
        __threadfence();
        int t = atomicAdd((int*)(accum + 2), 1);
        if (t == BN - 1) {
            const float total = atomicAdd(&accum[0], 0.f);
            const float cnt   = atomicAdd(&accum[1], 0.f);
            out[0] = (cnt > 0.f) ? (total / fmaxf(cnt, 1.f)) : 0.f;
        }
    }
}

extern "C" void kernel_launch(void* const* d_in, const int* in_sizes, int n_in,
                              void* d_out, int out_size, void* d_ws, size_t ws_size,
                              hipStream_t stream) {
    const float* emb    = (const float*)d_in[0];
    const int*   labels = (const int*)d_in[1];
    float*       out    = (float*)d_out;
    float*       accum  = (float*)d_ws;  // 3 words: sum, cnt, ticket

    hipMemsetAsync(accum, 0, 3 * sizeof(float), stream);
    triplet_fused_kernel<<<BN, NT, 0, stream>>>(emb, labels, accum, out);
}

// Round 7
// 73.834 us; speedup vs baseline: 1.7450x; 1.1555x over previous
//
#include <hip/hip_runtime.h>

#define BN 512
#define DIM 128
#define TMARGIN 0.3f
#define NT 256
#define NW 4   // waves per block

#define FMA4(ACC, U, V)                                                \
    ACC.x += U.x * V.x; ACC.y += U.y * V.y;                            \
    ACC.z += U.z * V.z; ACC.w += U.w * V.w;

__device__ __forceinline__ float hsum4(float4 v) {
    return (v.x + v.y) + (v.z + v.w);
}

// ---------------------------------------------------------------------------
// One block per anchor i (512 blocks, 2/CU).
// Phase A: dist row i, wave-cooperative coalesced loads.
// Phase B: semi-hard scan.
// Epilogue: fence-free — per-block partial slots (agent atomic stores) +
// one release ticket RMW; last block reduces the 512 slots.
// Workspace layout: psum[512] | pcnt[512] | ticket(int).
// ---------------------------------------------------------------------------
__global__ __launch_bounds__(NT, 2) void triplet_fused_kernel(
        const float* __restrict__ emb,
        const int* __restrict__ labels,
        float* __restrict__ ws,
        float* __restrict__ out) {
    const int i    = blockIdx.x;
    const int tid  = threadIdx.x;
    const int lane = tid & 63;
    const int wave = tid >> 6;

    float* psum   = ws;
    float* pcnt   = ws + BN;
    int*   ticket = (int*)(ws + 2 * BN);

    __shared__ float4 ei4[DIM / 4];   // anchor row (512 B)
    __shared__ float  drow[BN];
    __shared__ int    lab[BN];
    __shared__ int    pos_idx[BN];
    __shared__ int    npos_s;
    __shared__ float  wsum[NW];
    __shared__ int    wcnt[NW];
    __shared__ int    is_last;

    const float4* emb4 = (const float4*)emb;

    if (tid < DIM / 4) ei4[tid] = emb4[(size_t)i * 32 + tid];
    lab[tid]       = labels[tid];
    lab[tid + 256] = labels[tid + 256];
    if (tid == 0) npos_s = 0;
    __syncthreads();

    // sq_i from LDS broadcasts
    float4 sqv = {0, 0, 0, 0};
#pragma unroll
    for (int q = 0; q < DIM / 4; ++q) { float4 u = ei4[q]; FMA4(sqv, u, u); }
    const float sq_i = hsum4(sqv);

    // ---------------- Phase A: dist row, coalesced ----------------
    const int rl = lane >> 2;   // row-in-group 0..15
    const int kl = lane & 3;    // k-lane 0..3
#pragma unroll
    for (int c = 0; c < 8; ++c) {
        const int r = c * 64 + wave * 16 + rl;
        float4 accd = {0, 0, 0, 0}, accq = {0, 0, 0, 0};
#pragma unroll
        for (int q = 0; q < 8; ++q) {
            const int k4 = kl + 4 * q;
            const float4 v = emb4[(size_t)r * 32 + k4];
            const float4 u = ei4[k4];
            FMA4(accd, u, v);
            FMA4(accq, v, v);
        }
        float dot = hsum4(accd);
        float sqj = hsum4(accq);
        dot += __shfl_down(dot, 1); dot += __shfl_down(dot, 2);
        sqj += __shfl_down(sqj, 1); sqj += __shfl_down(sqj, 2);
        if (kl == 0) {
            const float d2 = sq_i + sqj - 2.f * dot;
            drow[r] = sqrtf(fmaxf(d2, 1e-12f));
        }
    }
    __syncthreads();

    // ---------------- Phase B: semi-hard scan ----------------
    const int li = lab[i];

    for (int j = tid; j < BN; j += NT) {
        if (lab[j] == li && j != i) {
            int p = atomicAdd(&npos_s, 1);
            pos_idx[p] = j;
        }
    }

    // Per-wave min over negatives + has_neg (barrier-free).
    float mn = 1e30f;
    int   hn = 0;
    for (int k = lane; k < BN; k += 64) {
        if (lab[k] != li) { hn = 1; mn = fminf(mn, drow[k]); }
    }
#pragma unroll
    for (int off = 32; off > 0; off >>= 1) {
        mn = fminf(mn, __shfl_down(mn, off));
        hn |= __shfl_down(hn, off);
    }
    mn = __shfl(mn, 0);
    hn = __shfl(hn, 0);
    __syncthreads();  // npos_s / pos_idx ready

    float lsum = 0.f;
    int   lcnt = 0;
    const int npos = npos_s;
    if (hn) {
        for (int p = wave; p < npos; p += NW) {
            const float dap = drow[pos_idx[p]];
            const float hi  = dap + TMARGIN;
            float smax = -1e30f;
            for (int k = lane; k < BN; k += 64) {
                const float dan = drow[k];
                if (lab[k] != li && dan > dap && dan < hi)
                    smax = fmaxf(smax, dan);
            }
#pragma unroll
            for (int off = 32; off > 0; off >>= 1)
                smax = fmaxf(smax, __shfl_down(smax, off));
            if (lane == 0) {
                const float dneg = (smax > -1e29f) ? smax : mn;
                lsum += fmaxf(dap - dneg + TMARGIN, 0.f);
                lcnt += 1;
            }
        }
    }
    if (lane == 0) { wsum[wave] = lsum; wcnt[wave] = lcnt; }
    __syncthreads();

    // ---------------- Epilogue: fence-free distributed reduce ----------------
    if (tid == 0) {
        float s = 0.f;
        int   c = 0;
#pragma unroll
        for (int w = 0; w < NW; ++w) { s += wsum[w]; c += wcnt[w]; }
        // Distinct slots — parallel coherent-point stores, no RMW contention.
        __hip_atomic_store(&psum[i], s,        __ATOMIC_RELAXED, __HIP_MEMORY_SCOPE_AGENT);
        __hip_atomic_store(&pcnt[i], (float)c, __ATOMIC_RELAXED, __HIP_MEMORY_SCOPE_AGENT);
        // Release RMW orders the two stores; no __threadfence needed.
        int t = __hip_atomic_fetch_add(ticket, 1, __ATOMIC_ACQ_REL,
                                       __HIP_MEMORY_SCOPE_AGENT);
        is_last = (t == BN - 1) ? 1 : 0;
    }
    __syncthreads();

    if (is_last) {
        // All 256 threads: coherent relaxed loads of the 512 partial slots.
        float s = __hip_atomic_load(&psum[tid], __ATOMIC_RELAXED, __HIP_MEMORY_SCOPE_AGENT)
                + __hip_atomic_load(&psum[tid + 256], __ATOMIC_RELAXED, __HIP_MEMORY_SCOPE_AGENT);
        float c = __hip_atomic_load(&pcnt[tid], __ATOMIC_RELAXED, __HIP_MEMORY_SCOPE_AGENT)
                + __hip_atomic_load(&pcnt[tid + 256], __ATOMIC_RELAXED, __HIP_MEMORY_SCOPE_AGENT);
#pragma unroll
        for (int off = 32; off > 0; off >>= 1) {
            s += __shfl_down(s, off);
            c += __shfl_down(c, off);
        }
        if (lane == 0) { wsum[wave] = s; wcnt[wave] = (int)c; }
        __syncthreads();
        if (tid == 0) {
            float total = 0.f; float cnt = 0.f;
#pragma unroll
            for (int w = 0; w < NW; ++w) { total += wsum[w]; cnt += (float)wcnt[w]; }
            out[0] = (cnt > 0.f) ? (total / fmaxf(cnt, 1.f)) : 0.f;
        }
    }
}

extern "C" void kernel_launch(void* const* d_in, const int* in_sizes, int n_in,
                              void* d_out, int out_size, void* d_ws, size_t ws_size,
                              hipStream_t stream) {
    const float* emb    = (const float*)d_in[0];
    const int*   labels = (const int*)d_in[1];
    float*       out    = (float*)d_out;
    float*       ws     = (float*)d_ws;  // psum[512] | pcnt[512] | ticket

    hipMemsetAsync(ws + 2 * BN, 0, sizeof(int), stream);  // zero the ticket only
    triplet_fused_kernel<<<BN, NT, 0, stream>>>(emb, labels, ws, out);
}

// Round 8
// 69.284 us; speedup vs baseline: 1.8596x; 1.0657x over previous
//
#include <hip/hip_runtime.h>

#define BN 512
#define DIM 128
#define TMARGIN 0.3f
#define NT 512
#define NW 8      // waves per block
#define NBLK 256  // 2 anchors per block

#define FMA4(ACC, U, V)                                                \
    ACC.x += U.x * V.x; ACC.y += U.y * V.y;                            \
    ACC.z += U.z * V.z; ACC.w += U.w * V.w;

__device__ __forceinline__ float hsum4(float4 v) {
    return (v.x + v.y) + (v.z + v.w);
}

// ---------------------------------------------------------------------------
// 256 blocks x 512 threads (1 block/CU, 8 waves). Block b handles anchors
// b and b+256. Phase A loads each row j once, dotting vs BOTH anchors
// (halves L1/L2 traffic vs 1-anchor blocks). Phase B: waves 0-3 scan anchor
// A, waves 4-7 anchor B. Epilogue: one plain-store partial per block; a tiny
// finalize kernel reduces (no ticket, no fence, no memset).
// ---------------------------------------------------------------------------
__global__ __launch_bounds__(NT, 1) void triplet_fused_kernel(
        const float* __restrict__ emb,
        const int* __restrict__ labels,
        float* __restrict__ psum,    // [NBLK]
        float* __restrict__ pcnt) {  // [NBLK]
    const int ia   = blockIdx.x;        // anchor A
    const int ib   = blockIdx.x + 256;  // anchor B
    const int tid  = threadIdx.x;
    const int lane = tid & 63;
    const int wave = tid >> 6;

    __shared__ float4 ea4[DIM / 4], eb4[DIM / 4];
    __shared__ float  drowA[BN], drowB[BN];
    __shared__ int    lab[BN];
    __shared__ int    posA[BN], posB[BN];
    __shared__ int    nposA, nposB;
    __shared__ float  wsum[NW];
    __shared__ int    wcnt[NW];

    const float4* emb4 = (const float4*)emb;

    if (tid < 32)                 ea4[tid]      = emb4[(size_t)ia * 32 + tid];
    else if (tid < 64)            eb4[tid - 32] = emb4[(size_t)ib * 32 + (tid - 32)];
    lab[tid] = labels[tid];
    if (tid == 0) { nposA = 0; nposB = 0; }
    __syncthreads();

    // squared norms of both anchors (per-thread from LDS broadcasts)
    float4 sva = {0,0,0,0}, svb = {0,0,0,0};
#pragma unroll
    for (int q = 0; q < DIM / 4; ++q) {
        float4 ua = ea4[q]; FMA4(sva, ua, ua);
        float4 ub = eb4[q]; FMA4(svb, ub, ub);
    }
    const float sqA = hsum4(sva);
    const float sqB = hsum4(svb);

    // ---------------- Phase A: both dist rows, one pass over emb ----------
    // 8 waves x 16 rows/iter; 4 lanes per row, 64 B contiguous per group.
    const int rl = lane >> 2;   // row-in-group 0..15
    const int kl = lane & 3;    // k-lane 0..3
#pragma unroll
    for (int c = 0; c < 4; ++c) {
        const int r = c * 128 + wave * 16 + rl;
        float4 da = {0,0,0,0}, db = {0,0,0,0}, qq = {0,0,0,0};
#pragma unroll
        for (int q = 0; q < 8; ++q) {
            const int k4 = kl + 4 * q;
            const float4 v  = emb4[(size_t)r * 32 + k4];
            const float4 ua = ea4[k4];
            const float4 ub = eb4[k4];
            FMA4(da, ua, v);
            FMA4(db, ub, v);
            FMA4(qq, v, v);
        }
        float dotA = hsum4(da), dotB = hsum4(db), sqj = hsum4(qq);
        dotA += __shfl_down(dotA, 1); dotA += __shfl_down(dotA, 2);
        dotB += __shfl_down(dotB, 1); dotB += __shfl_down(dotB, 2);
        sqj  += __shfl_down(sqj, 1);  sqj  += __shfl_down(sqj, 2);
        if (kl == 0) {
            drowA[r] = sqrtf(fmaxf(sqA + sqj - 2.f * dotA, 1e-12f));
            drowB[r] = sqrtf(fmaxf(sqB + sqj - 2.f * dotB, 1e-12f));
        }
    }

    // positives lists (threads 0-255 -> A, 256-511 -> B)
    {
        const int grp = tid >> 8;           // 0: A, 1: B
        const int t   = tid & 255;
        const int li  = grp ? lab[ib] : lab[ia];
        const int self = grp ? ib : ia;
        int* plist = grp ? posB : posA;
        int* pn    = grp ? &nposB : &nposA;
        for (int j = t; j < BN; j += 256) {
            if (lab[j] == li && j != self) {
                int p = atomicAdd(pn, 1);
                plist[p] = j;
            }
        }
    }
    __syncthreads();

    // ---------------- Phase B: waves 0-3 anchor A, 4-7 anchor B -----------
    const int grp   = wave >> 2;            // 0: A, 1: B
    const int wsub  = wave & 3;
    const float* drow = grp ? drowB : drowA;
    const int*  plist = grp ? posB  : posA;
    const int   npos  = grp ? nposB : nposA;
    const int   li    = grp ? lab[ib] : lab[ia];

    // per-wave min over negatives + has_neg
    float mn = 1e30f;
    int   hn = 0;
    for (int k = lane; k < BN; k += 64) {
        if (lab[k] != li) { hn = 1; mn = fminf(mn, drow[k]); }
    }
#pragma unroll
    for (int off = 32; off > 0; off >>= 1) {
        mn = fminf(mn, __shfl_down(mn, off));
        hn |= __shfl_down(hn, off);
    }
    mn = __shfl(mn, 0);
    hn = __shfl(hn, 0);

    float lsum = 0.f;
    int   lcnt = 0;
    if (hn) {
        for (int p = wsub; p < npos; p += 4) {
            const float dap = drow[plist[p]];
            const float hi  = dap + TMARGIN;
            float smax = -1e30f;
            for (int k = lane; k < BN; k += 64) {
                const float dan = drow[k];
                if (lab[k] != li && dan > dap && dan < hi)
                    smax = fmaxf(smax, dan);
            }
#pragma unroll
            for (int off = 32; off > 0; off >>= 1)
                smax = fmaxf(smax, __shfl_down(smax, off));
            if (lane == 0) {
                const float dneg = (smax > -1e29f) ? smax : mn;
                lsum += fmaxf(dap - dneg + TMARGIN, 0.f);
                lcnt += 1;
            }
        }
    }
    if (lane == 0) { wsum[wave] = lsum; wcnt[wave] = lcnt; }
    __syncthreads();

    // one combined partial per block; plain stores (kernel-end flush)
    if (tid == 0) {
        float s = 0.f;
        int   c = 0;
#pragma unroll
        for (int w = 0; w < NW; ++w) { s += wsum[w]; c += wcnt[w]; }
        psum[blockIdx.x] = s;
        pcnt[blockIdx.x] = (float)c;
    }
}

// ---------------------------------------------------------------------------
// Finalize: one block reduces the 256 partial slots.
// ---------------------------------------------------------------------------
__global__ __launch_bounds__(256) void finalize_kernel(
        const float* __restrict__ psum,
        const float* __restrict__ pcnt,
        float* __restrict__ out) {
    const int tid  = threadIdx.x;
    const int lane = tid & 63;
    const int wave = tid >> 6;
    __shared__ float ws_[4], wc_[4];

    float s = psum[tid];
    float c = pcnt[tid];
#pragma unroll
    for (int off = 32; off > 0; off >>= 1) {
        s += __shfl_down(s, off);
        c += __shfl_down(c, off);
    }
    if (lane == 0) { ws_[wave] = s; wc_[wave] = c; }
    __syncthreads();
    if (tid == 0) {
        float total = ws_[0] + ws_[1] + ws_[2] + ws_[3];
        float cnt   = wc_[0] + wc_[1] + wc_[2] + wc_[3];
        out[0] = (cnt > 0.f) ? (total / fmaxf(cnt, 1.f)) : 0.f;
    }
}

extern "C" void kernel_launch(void* const* d_in, const int* in_sizes, int n_in,
                              void* d_out, int out_size, void* d_ws, size_t ws_size,
                              hipStream_t stream) {
    const float* emb    = (const float*)d_in[0];
    const int*   labels = (const int*)d_in[1];
    float*       out    = (float*)d_out;
    float*       psum   = (float*)d_ws;        // [256]
    float*       pcnt   = psum + NBLK;         // [256]

    triplet_fused_kernel<<<NBLK, NT, 0, stream>>>(emb, labels, psum, pcnt);
    finalize_kernel<<<1, 256, 0, stream>>>(psum, pcnt, out);
}